// Round 3
// baseline (580.543 us; speedup 1.0000x reference)
//
// Round 2 resubmission — rounds 1-2 failed with broker-side UnresponsiveContainer
// (job never delivered); kernel source unchanged semantically.
#include <hip/hip_runtime.h>
#include <hip/hip_bf16.h>
#include <cstdint>
#include <cstddef>

#define N_NODES 10000
#define KNN_K 20
#define NEDGE (N_NODES * KNN_K)

using bf16x8 = __attribute__((ext_vector_type(8))) short;
using f32x4  = __attribute__((ext_vector_type(4))) float;

__device__ __forceinline__ float bf_lo(unsigned int u) {
  union { unsigned int i; float f; } c; c.i = u << 16; return c.f;
}
__device__ __forceinline__ float bf_hi(unsigned int u) {
  union { unsigned int i; float f; } c; c.i = u & 0xFFFF0000u; return c.f;
}
__device__ __forceinline__ unsigned short f2bf(float f) {
  union { float f; unsigned int i; } c; c.f = f;
  unsigned int u = c.i;
  u += 0x7FFFu + ((u >> 16) & 1u);   // RNE
  return (unsigned short)(u >> 16);
}

__device__ __forceinline__ void gll16(const void* g, void* l) {
  __builtin_amdgcn_global_load_lds(
      (const __attribute__((address_space(1))) unsigned int*)g,
      (__attribute__((address_space(3))) unsigned int*)l,
      16, 0, 0);
}

// ---------------- transpose f32 [srows][scols] -> bf16 dst[col][dcol0 + row] ----------------
__global__ __launch_bounds__(256) void transpose_f32_bf16(
    const float* __restrict__ src0, unsigned short* __restrict__ dst,
    int srows, int scols, int dstride, size_t slice_elems, int dcol_per_slice)
{
  __shared__ float lds[64 * 65];
  const int z = blockIdx.z;
  const float* src = src0 + (size_t)z * slice_elems;
  const int dcol0 = z * dcol_per_slice;
  const int c0 = blockIdx.x * 64;
  const int r0 = blockIdx.y * 64;
  const int tid = threadIdx.x;
#pragma unroll
  for (int q = 0; q < 4; ++q) {
    int unit = q * 256 + tid;            // 1024 float4 units
    int rr = unit >> 4;                  // 0..63
    int cu = unit & 15;                  // 0..15
    int r = r0 + rr, c = c0 + cu * 4;
    float4 v = make_float4(0.f, 0.f, 0.f, 0.f);
    if (r < srows && c + 3 < scols) v = *(const float4*)&src[(size_t)r * scols + c];
    lds[rr * 65 + cu * 4 + 0] = v.x;
    lds[rr * 65 + cu * 4 + 1] = v.y;
    lds[rr * 65 + cu * 4 + 2] = v.z;
    lds[rr * 65 + cu * 4 + 3] = v.w;
  }
  __syncthreads();
#pragma unroll
  for (int q = 0; q < 2; ++q) {
    int unit = q * 256 + tid;            // 512 units of 8 bf16
    int cl = unit >> 3;                  // src col within tile (= dst row)
    int ru = unit & 7;
    int c = c0 + cl;
    if (c < scols) {
      unsigned short tmp[8];
#pragma unroll
      for (int j = 0; j < 8; ++j) tmp[j] = f2bf(lds[(ru * 8 + j) * 65 + cl]);
      uint4 o;
      o.x = (unsigned int)tmp[0] | ((unsigned int)tmp[1] << 16);
      o.y = (unsigned int)tmp[2] | ((unsigned int)tmp[3] << 16);
      o.z = (unsigned int)tmp[4] | ((unsigned int)tmp[5] << 16);
      o.w = (unsigned int)tmp[6] | ((unsigned int)tmp[7] << 16);
      *(uint4*)&dst[(size_t)c * dstride + dcol0 + r0 + ru * 8] = o;
    }
  }
}

// ---------------- kNN: wave per node, wave-shared distributed top-20 ----------------
__device__ __forceinline__ float wave_max6(float v) {
  v = fmaxf(v, __shfl_xor(v, 1));
  v = fmaxf(v, __shfl_xor(v, 2));
  v = fmaxf(v, __shfl_xor(v, 4));
  v = fmaxf(v, __shfl_xor(v, 8));
  v = fmaxf(v, __shfl_xor(v, 16));
  v = fmaxf(v, __shfl_xor(v, 32));
  return v;
}

__global__ __launch_bounds__(256) void knn_kernel(
    const float* __restrict__ pos, int* __restrict__ knn_out)
{
  __shared__ float4 tile[256];
  const int tid = threadIdx.x, lane = tid & 63, wave = tid >> 6;
  const int i = blockIdx.x * 4 + wave;
  const float xi = pos[i * 3 + 0], yi = pos[i * 3 + 1], zi = pos[i * 3 + 2];
  const float sqi = xi * xi + yi * yi + zi * zi;
  const float INF = __builtin_inff();
  float held_d = (lane < KNN_K) ? INF : -INF;
  int held_i = 0;
  float tau = INF;
  for (int t = 0; t < 40; ++t) {
    const int nb = t * 256;
    __syncthreads();
    {
      int c = nb + tid;
      float4 v;
      if (c < N_NODES) {
        float x = pos[c * 3 + 0], y = pos[c * 3 + 1], z = pos[c * 3 + 2];
        v = make_float4(x, y, z, x * x + y * y + z * z);
      } else v = make_float4(0.f, 0.f, 0.f, INF);
      tile[tid] = v;
    }
    __syncthreads();
    const int lim = N_NODES - nb;
    const int nsub = (lim >= 256) ? 4 : ((lim + 63) >> 6);
    for (int sub = 0; sub < nsub; ++sub) {
      const int cidx = nb + sub * 64 + lane;
      float4 s = tile[sub * 64 + lane];
      float dotv = xi * s.x + yi * s.y + zi * s.z;
      float d = sqi + s.w - 2.0f * dotv;          // matches ref formula
      if (cidx == i) d = INF;                      // self-exclusion (and OOB has s.w=INF)
      unsigned long long mask = __ballot(d < tau);
      bool did = false;
      if (t == 0 && sub == 0) {
        if (lane < KNN_K) { held_d = d; held_i = cidx; }
        mask &= ~((1ull << KNN_K) - 1ull);
        did = true;
      }
      while (mask) {
        const int sl = __ffsll(mask) - 1;
        mask &= mask - 1;
        const float cd = __shfl(d, sl);
        const int ci = __shfl(cidx, sl);
        tau = wave_max6(held_d);                   // current 20th-smallest (max of held)
        if (cd < tau) {
          unsigned long long em = __ballot(held_d == tau);
          int rl = __ffsll(em) - 1;                // replace one max slot
          if (lane == rl) { held_d = cd; held_i = ci; }
          did = true;
        }
      }
      if (did) tau = wave_max6(held_d);
    }
  }
  if (lane < KNN_K) knn_out[i * KNN_K + lane] = held_i;
}

// ---------------- reverse-CSR build ----------------
__global__ __launch_bounds__(256) void count_kernel(
    const int* __restrict__ knn, int* __restrict__ counts)
{
  int e = blockIdx.x * 256 + threadIdx.x;
  if (e < NEDGE) atomicAdd(&counts[knn[e]], 1);
}

__global__ __launch_bounds__(256) void scan_kernel(
    const int* __restrict__ counts, int* __restrict__ rptr)
{
  __shared__ int part[256];
  const int tid = threadIdx.x;
  const int base = tid * 40;                       // 256*40 = 10240 >= 10000
  int s = 0;
  for (int q = 0; q < 40; ++q) { int idx = base + q; if (idx < N_NODES) s += counts[idx]; }
  part[tid] = s;
  __syncthreads();
  for (int off = 1; off < 256; off <<= 1) {
    int add = (tid >= off) ? part[tid - off] : 0;
    __syncthreads();
    part[tid] += add;
    __syncthreads();
  }
  int run = part[tid] - s;                         // exclusive offset
  for (int q = 0; q < 40; ++q) {
    int idx = base + q;
    if (idx < N_NODES) { rptr[idx] = run; run += counts[idx]; }
  }
  if (tid == 255) rptr[N_NODES] = run;
}

__global__ __launch_bounds__(256) void fill_kernel(
    const int* __restrict__ knn, const int* __restrict__ rptr,
    int* __restrict__ cursor, int* __restrict__ rsrc)
{
  int e = blockIdx.x * 256 + threadIdx.x;
  if (e < NEDGE) {
    int j = knn[e];
    int i = e / KNN_K;
    int p = atomicAdd(&cursor[j], 1);
    rsrc[rptr[j] + p] = i;
  }
}

// sort each reverse-adjacency list -> deterministic gather order
__global__ __launch_bounds__(256) void sort_kernel(
    const int* __restrict__ rptr, int* __restrict__ rsrc)
{
  int j = blockIdx.x * 256 + threadIdx.x;
  if (j < N_NODES) {
    int s0 = rptr[j], s1 = rptr[j + 1];
    for (int a = s0 + 1; a < s1; ++a) {
      int v = rsrc[a];
      int b = a - 1;
      while (b >= s0 && rsrc[b] > v) { rsrc[b + 1] = rsrc[b]; --b; }
      rsrc[b + 1] = v;
    }
  }
}

// ---------------- prop: out[j] = scale2 * sum_{i in rev(j)} t[i]  - prev[j] ----------------
__global__ __launch_bounds__(256) void prop_kernel(
    const unsigned short* __restrict__ tin, const unsigned short* __restrict__ tprev,
    unsigned short* __restrict__ tout, const int* __restrict__ rptr,
    const int* __restrict__ rsrc, float scale2)
{
  const int wave = threadIdx.x >> 6, lane = threadIdx.x & 63;
  const int j = blockIdx.x * 4 + wave;
  const int s0 = rptr[j], s1 = rptr[j + 1];
  const size_t coff = (size_t)lane * 8;
  float acc[8] = {0.f, 0.f, 0.f, 0.f, 0.f, 0.f, 0.f, 0.f};
  for (int s = s0; s < s1; ++s) {
    int src = rsrc[s];
    uint4 v = *(const uint4*)&tin[(size_t)src * 512 + coff];
    acc[0] += bf_lo(v.x); acc[1] += bf_hi(v.x);
    acc[2] += bf_lo(v.y); acc[3] += bf_hi(v.y);
    acc[4] += bf_lo(v.z); acc[5] += bf_hi(v.z);
    acc[6] += bf_lo(v.w); acc[7] += bf_hi(v.w);
  }
  float pv[8] = {0.f, 0.f, 0.f, 0.f, 0.f, 0.f, 0.f, 0.f};
  if (tprev != nullptr) {
    uint4 p = *(const uint4*)&tprev[(size_t)j * 512 + coff];
    pv[0] = bf_lo(p.x); pv[1] = bf_hi(p.x);
    pv[2] = bf_lo(p.y); pv[3] = bf_hi(p.y);
    pv[4] = bf_lo(p.z); pv[5] = bf_hi(p.z);
    pv[6] = bf_lo(p.w); pv[7] = bf_hi(p.w);
  }
  unsigned short o16[8];
#pragma unroll
  for (int q = 0; q < 8; ++q) o16[q] = f2bf(scale2 * acc[q] - pv[q]);
  uint4 o;
  o.x = (unsigned int)o16[0] | ((unsigned int)o16[1] << 16);
  o.y = (unsigned int)o16[2] | ((unsigned int)o16[3] << 16);
  o.z = (unsigned int)o16[4] | ((unsigned int)o16[5] << 16);
  o.w = (unsigned int)o16[6] | ((unsigned int)o16[7] << 16);
  *(uint4*)&tout[(size_t)j * 512 + coff] = o;
}

// ---------------- GEMM: C[o][n] = sum_kc A[n][kc] * B[kc][o] + bias[o] ----------------
// A = TxAll bf16: 5 blocks of [10000][512] (+pad). B^T = thetabT bf16 [512][2560].
__global__ __launch_bounds__(256) void gemm_kernel(
    const unsigned short* __restrict__ A,
    const unsigned short* __restrict__ Bt,
    const float* __restrict__ bias,
    float* __restrict__ C)
{
  __shared__ __align__(16) char smem[64 * 132 * 4];   // 33792B: tiles(32KB) / epilogue(33KB)
  unsigned short* As = (unsigned short*)smem;         // [128][64] bf16
  unsigned short* Bs = As + 128 * 64;                 // [128 o][64 k] bf16
  float* eps = (float*)smem;                          // [64 o][132] f32

  const int tid = threadIdx.x;
  const int wave = tid >> 6, lane = tid & 63;
  const int l15 = lane & 15, hi = lane >> 4;
  const int wr = wave >> 1, wc = wave & 1;
  const int n0 = blockIdx.x * 128;
  const int o0 = blockIdx.y * 128;

  f32x4 acc[4][4];
#pragma unroll
  for (int a = 0; a < 4; ++a)
#pragma unroll
    for (int b = 0; b < 4; ++b) acc[a][b] = (f32x4){0.f, 0.f, 0.f, 0.f};

  for (int kt = 0; kt < 40; ++kt) {
    const int k0 = kt * 64;
    const int ko = k0 >> 9;
    const int c0 = k0 & 511;
    const unsigned short* Ab = A + (size_t)ko * ((size_t)N_NODES * 512);
#pragma unroll
    for (int q = 0; q < 4; ++q) {
      int idx = (wave * 4 + q) * 64 + lane;     // 16B unit id, 0..1023
      int r = idx >> 3, u = idx & 7;
      gll16(Ab + (size_t)(n0 + r) * 512 + c0 + u * 8, As + (size_t)(wave * 4 + q) * 512);
    }
#pragma unroll
    for (int q = 0; q < 4; ++q) {
      int idx = (wave * 4 + q) * 64 + lane;
      int r = idx >> 3, u = idx & 7;
      gll16(Bt + (size_t)(o0 + r) * 2560 + k0 + u * 8, Bs + (size_t)(wave * 4 + q) * 512);
    }
    __syncthreads();
#pragma unroll
    for (int kk = 0; kk < 2; ++kk) {
      bf16x8 af[4], bfr[4];
#pragma unroll
      for (int mi = 0; mi < 4; ++mi)
        af[mi] = *(const bf16x8*)(As + ((wr * 64 + mi * 16 + l15) * 64 + kk * 32 + hi * 8));
#pragma unroll
      for (int ni = 0; ni < 4; ++ni)
        bfr[ni] = *(const bf16x8*)(Bs + ((wc * 64 + ni * 16 + l15) * 64 + kk * 32 + hi * 8));
#pragma unroll
      for (int mi = 0; mi < 4; ++mi)
#pragma unroll
        for (int ni = 0; ni < 4; ++ni)
          acc[mi][ni] = __builtin_amdgcn_mfma_f32_16x16x32_bf16(af[mi], bfr[ni], acc[mi][ni], 0, 0, 0);
    }
    __syncthreads();
  }

  // epilogue: LDS-transposed coalesced store of C[o][n] + bias
#pragma unroll
  for (int h = 0; h < 2; ++h) {
    __syncthreads();
    if (wc == h) {
#pragma unroll
      for (int mi = 0; mi < 4; ++mi)
#pragma unroll
        for (int ni = 0; ni < 4; ++ni) {
          int o_l = ni * 16 + l15;                   // 0..63 within half
          int nb = wr * 64 + mi * 16 + hi * 4;       // 0..124, x4 aligned
          *(f32x4*)&eps[o_l * 132 + nb] = acc[mi][ni];
        }
    }
    __syncthreads();
#pragma unroll
    for (int q = 0; q < 8; ++q) {
      int unit = q * 256 + tid;                      // 2048 float4 units
      int o_l = unit >> 5, nu = unit & 31;
      int n = n0 + nu * 4;
      if (n < N_NODES) {
        int o = o0 + h * 64 + o_l;
        f32x4 v = *(const f32x4*)&eps[o_l * 132 + nu * 4];
        float bo = bias[o];
        v = v + bo;
        *(f32x4*)&C[(size_t)o * N_NODES + n] = v;
      }
    }
  }
}

extern "C" void kernel_launch(void* const* d_in, const int* in_sizes, int n_in,
                              void* d_out, int out_size, void* d_ws, size_t ws_size,
                              hipStream_t stream)
{
  const float* x        = (const float*)d_in[0];   // [512][10000]
  const float* position = (const float*)d_in[1];   // [10000][3]
  const float* theta    = (const float*)d_in[2];   // [5][512][512]
  const float* bias     = (const float*)d_in[3];   // [512]

  char* ws = (char*)d_ws;
  size_t off = 0;
  auto alloc = [&](size_t bytes) -> void* {
    void* p = ws + off;
    off = (off + bytes + 255) & ~(size_t)255;
    return p;
  };
  unsigned short* TxAll   = (unsigned short*)alloc(5ull * N_NODES * 512 * 2 + 131072); // +128-row pad
  unsigned short* thetabT = (unsigned short*)alloc(512ull * 2560 * 2);
  int* knn    = (int*)alloc((size_t)NEDGE * 4);
  int* rptr   = (int*)alloc((size_t)(N_NODES + 1) * 4);
  int* counts = (int*)alloc((size_t)N_NODES * 4);
  int* cursor = (int*)alloc((size_t)N_NODES * 4);
  int* rsrc   = (int*)alloc((size_t)NEDGE * 4);
  if (ws_size < off) return;   // insufficient scratch

  // theta [5][512][512] -> thetabT [o=512][kc=2560]
  transpose_f32_bf16<<<dim3(8, 8, 5), 256, 0, stream>>>(
      theta, thetabT, 512, 512, 2560, (size_t)512 * 512, 512);
  // x [512][10000] -> Tx0 [10000][512]
  transpose_f32_bf16<<<dim3(157, 8, 1), 256, 0, stream>>>(
      x, TxAll, 512, N_NODES, 512, 0, 0);

  knn_kernel<<<2500, 256, 0, stream>>>(position, knn);

  hipMemsetAsync(counts, 0, (size_t)N_NODES * 4, stream);
  hipMemsetAsync(cursor, 0, (size_t)N_NODES * 4, stream);
  count_kernel<<<(NEDGE + 255) / 256, 256, 0, stream>>>(knn, counts);
  scan_kernel<<<1, 256, 0, stream>>>(counts, rptr);
  fill_kernel<<<(NEDGE + 255) / 256, 256, 0, stream>>>(knn, rptr, cursor, rsrc);
  sort_kernel<<<(N_NODES + 255) / 256, 256, 0, stream>>>(rptr, rsrc);

  unsigned short* Tx0 = TxAll;
  unsigned short* Tx1 = TxAll + 1ull * N_NODES * 512;
  unsigned short* Tx2 = TxAll + 2ull * N_NODES * 512;
  unsigned short* Tx3 = TxAll + 3ull * N_NODES * 512;
  unsigned short* Tx4 = TxAll + 4ull * N_NODES * 512;

  // Tx1 = prop(Tx0) = -0.05*sum ; Tx_k = 2*prop(Tx_{k-1}) - Tx_{k-2} = -0.10*sum - prev
  prop_kernel<<<2500, 256, 0, stream>>>(Tx0, nullptr, Tx1, rptr, rsrc, -0.05f);
  prop_kernel<<<2500, 256, 0, stream>>>(Tx1, Tx0,     Tx2, rptr, rsrc, -0.10f);
  prop_kernel<<<2500, 256, 0, stream>>>(Tx2, Tx1,     Tx3, rptr, rsrc, -0.10f);
  prop_kernel<<<2500, 256, 0, stream>>>(Tx3, Tx2,     Tx4, rptr, rsrc, -0.10f);

  gemm_kernel<<<dim3(79, 4), 256, 0, stream>>>(TxAll, thetabT, bias, (float*)d_out);
}

// Round 5
// 488.063 us; speedup vs baseline: 1.1895x; 1.1895x over previous
//
// Round 5: kNN with lossless u64 keys (fp32 dist bits << 32 | idx) — fixes the
// 0.39 absmax regression from round-4's 18-bit quantized keys while keeping the
// branchless per-lane top-8 insert network. Rest unchanged from round-3 pass.
#include <hip/hip_runtime.h>
#include <hip/hip_bf16.h>
#include <cstdint>
#include <cstddef>

#define N_NODES 10000
#define KNN_K 20
#define NEDGE (N_NODES * KNN_K)
#define NBATCH 157                 // ceil(10000/64)
#define POS4_PAD 10048             // 157*64

using bf16x8 = __attribute__((ext_vector_type(8))) short;
using f32x4  = __attribute__((ext_vector_type(4))) float;

__device__ __forceinline__ float bf_lo(unsigned int u) {
  union { unsigned int i; float f; } c; c.i = u << 16; return c.f;
}
__device__ __forceinline__ float bf_hi(unsigned int u) {
  union { unsigned int i; float f; } c; c.i = u & 0xFFFF0000u; return c.f;
}
__device__ __forceinline__ unsigned short f2bf(float f) {
  union { float f; unsigned int i; } c; c.f = f;
  unsigned int u = c.i;
  u += 0x7FFFu + ((u >> 16) & 1u);   // RNE
  return (unsigned short)(u >> 16);
}

__device__ __forceinline__ unsigned long long umin64(unsigned long long a, unsigned long long b) {
  return a < b ? a : b;
}
__device__ __forceinline__ unsigned long long umax64(unsigned long long a, unsigned long long b) {
  return a > b ? a : b;
}

__device__ __forceinline__ void gll16(const void* g, void* l) {
  __builtin_amdgcn_global_load_lds(
      (const __attribute__((address_space(1))) unsigned int*)g,
      (__attribute__((address_space(3))) unsigned int*)l,
      16, 0, 0);
}

// ---------------- transpose f32 [srows][scols] -> bf16 dst[col][dcol0 + row] ----------------
__global__ __launch_bounds__(256) void transpose_f32_bf16(
    const float* __restrict__ src0, unsigned short* __restrict__ dst,
    int srows, int scols, int dstride, size_t slice_elems, int dcol_per_slice)
{
  __shared__ float lds[64 * 65];
  const int z = blockIdx.z;
  const float* src = src0 + (size_t)z * slice_elems;
  const int dcol0 = z * dcol_per_slice;
  const int c0 = blockIdx.x * 64;
  const int r0 = blockIdx.y * 64;
  const int tid = threadIdx.x;
#pragma unroll
  for (int q = 0; q < 4; ++q) {
    int unit = q * 256 + tid;            // 1024 float4 units
    int rr = unit >> 4;                  // 0..63
    int cu = unit & 15;                  // 0..15
    int r = r0 + rr, c = c0 + cu * 4;
    float4 v = make_float4(0.f, 0.f, 0.f, 0.f);
    if (r < srows && c + 3 < scols) v = *(const float4*)&src[(size_t)r * scols + c];
    lds[rr * 65 + cu * 4 + 0] = v.x;
    lds[rr * 65 + cu * 4 + 1] = v.y;
    lds[rr * 65 + cu * 4 + 2] = v.z;
    lds[rr * 65 + cu * 4 + 3] = v.w;
  }
  __syncthreads();
#pragma unroll
  for (int q = 0; q < 2; ++q) {
    int unit = q * 256 + tid;            // 512 units of 8 bf16
    int cl = unit >> 3;                  // src col within tile (= dst row)
    int ru = unit & 7;
    int c = c0 + cl;
    if (c < scols) {
      unsigned short tmp[8];
#pragma unroll
      for (int j = 0; j < 8; ++j) tmp[j] = f2bf(lds[(ru * 8 + j) * 65 + cl]);
      uint4 o;
      o.x = (unsigned int)tmp[0] | ((unsigned int)tmp[1] << 16);
      o.y = (unsigned int)tmp[2] | ((unsigned int)tmp[3] << 16);
      o.z = (unsigned int)tmp[4] | ((unsigned int)tmp[5] << 16);
      o.w = (unsigned int)tmp[6] | ((unsigned int)tmp[7] << 16);
      *(uint4*)&dst[(size_t)c * dstride + dcol0 + r0 + ru * 8] = o;
    }
  }
}

// ---------------- pos4: pack (x,y,z,|p|^2) ----------------
__global__ __launch_bounds__(256) void pos4_kernel(
    const float* __restrict__ pos, float4* __restrict__ pos4)
{
  int c = blockIdx.x * 256 + threadIdx.x;
  if (c < N_NODES) {
    float x = pos[c * 3 + 0], y = pos[c * 3 + 1], z = pos[c * 3 + 2];
    pos4[c] = make_float4(x, y, z, x * x + y * y + z * z);
  }
}

// ---------------- kNN: wave per node, per-lane register top-8 (u64 keys) ----------------
__global__ __launch_bounds__(256) void knn_kernel(
    const float4* __restrict__ pos4, int* __restrict__ knn_out)
{
  const int lane = threadIdx.x & 63, wave = threadIdx.x >> 6;
  const int i = blockIdx.x * 4 + wave;
  const float4 pi = pos4[i];
  const unsigned long long SENT = ~0ull;

  unsigned long long r0 = SENT, r1 = SENT, r2 = SENT, r3 = SENT;
  unsigned long long r4 = SENT, r5 = SENT, r6 = SENT, r7 = SENT;

#pragma unroll 4
  for (int b = 0; b < NBATCH; ++b) {
    const int cid = b * 64 + lane;                 // < POS4_PAD; pad masked below
    const float4 s = pos4[cid];
    float d = pi.w + s.w - 2.0f * (pi.x * s.x + pi.y * s.y + pi.z * s.z);
    d = fmaxf(d, 0.0f);                            // keep uint ordering valid
    unsigned long long k =
        ((unsigned long long)__float_as_uint(d) << 32) | (unsigned int)cid;
    if (cid == i || cid >= N_NODES) k = SENT;
    // unconditional sorted insert, keep 8 smallest (ascending r0..r7)
    r7 = umin64(r7, umax64(r6, k));
    r6 = umin64(r6, umax64(r5, k));
    r5 = umin64(r5, umax64(r4, k));
    r4 = umin64(r4, umax64(r3, k));
    r3 = umin64(r3, umax64(r2, k));
    r2 = umin64(r2, umax64(r1, k));
    r1 = umin64(r1, umax64(r0, k));
    r0 = umin64(r0, k);
  }

  // merge: 20 rounds of wave-wide extract-min over per-lane sorted lists
  unsigned int keep = 0;
#pragma unroll
  for (int r = 0; r < KNN_K; ++r) {
    unsigned long long m = r0;
    m = umin64(m, (unsigned long long)__shfl_xor((long long)m, 1));
    m = umin64(m, (unsigned long long)__shfl_xor((long long)m, 2));
    m = umin64(m, (unsigned long long)__shfl_xor((long long)m, 4));
    m = umin64(m, (unsigned long long)__shfl_xor((long long)m, 8));
    m = umin64(m, (unsigned long long)__shfl_xor((long long)m, 16));
    m = umin64(m, (unsigned long long)__shfl_xor((long long)m, 32));
    if (r0 == m) {                                  // unique keys: exactly one lane
      r0 = r1; r1 = r2; r2 = r3; r3 = r4; r4 = r5; r5 = r6; r6 = r7;
      r7 = SENT;
    }
    if (lane == r) keep = (unsigned int)m;          // low 32 bits = candidate id
  }
  if (lane < KNN_K) knn_out[i * KNN_K + lane] = (int)keep;
}

// ---------------- reverse-CSR build ----------------
__global__ __launch_bounds__(256) void count_kernel(
    const int* __restrict__ knn, int* __restrict__ counts)
{
  int e = blockIdx.x * 256 + threadIdx.x;
  if (e < NEDGE) atomicAdd(&counts[knn[e]], 1);
}

__global__ __launch_bounds__(256) void scan_kernel(
    const int* __restrict__ counts, int* __restrict__ rptr)
{
  __shared__ int part[256];
  const int tid = threadIdx.x;
  const int base = tid * 40;                       // 256*40 = 10240 >= 10000
  int s = 0;
  for (int q = 0; q < 40; ++q) { int idx = base + q; if (idx < N_NODES) s += counts[idx]; }
  part[tid] = s;
  __syncthreads();
  for (int off = 1; off < 256; off <<= 1) {
    int add = (tid >= off) ? part[tid - off] : 0;
    __syncthreads();
    part[tid] += add;
    __syncthreads();
  }
  int run = part[tid] - s;                         // exclusive offset
  for (int q = 0; q < 40; ++q) {
    int idx = base + q;
    if (idx < N_NODES) { rptr[idx] = run; run += counts[idx]; }
  }
  if (tid == 255) rptr[N_NODES] = run;
}

__global__ __launch_bounds__(256) void fill_kernel(
    const int* __restrict__ knn, const int* __restrict__ rptr,
    int* __restrict__ cursor, int* __restrict__ rsrc)
{
  int e = blockIdx.x * 256 + threadIdx.x;
  if (e < NEDGE) {
    int j = knn[e];
    int i = e / KNN_K;
    int p = atomicAdd(&cursor[j], 1);
    rsrc[rptr[j] + p] = i;
  }
}

// sort each reverse-adjacency list -> deterministic gather order
__global__ __launch_bounds__(256) void sort_kernel(
    const int* __restrict__ rptr, int* __restrict__ rsrc)
{
  int j = blockIdx.x * 256 + threadIdx.x;
  if (j < N_NODES) {
    int s0 = rptr[j], s1 = rptr[j + 1];
    for (int a = s0 + 1; a < s1; ++a) {
      int v = rsrc[a];
      int b = a - 1;
      while (b >= s0 && rsrc[b] > v) { rsrc[b + 1] = rsrc[b]; --b; }
      rsrc[b + 1] = v;
    }
  }
}

// ---------------- prop: out[j] = scale2 * sum_{i in rev(j)} t[i]  - prev[j] ----------------
__global__ __launch_bounds__(256) void prop_kernel(
    const unsigned short* __restrict__ tin, const unsigned short* __restrict__ tprev,
    unsigned short* __restrict__ tout, const int* __restrict__ rptr,
    const int* __restrict__ rsrc, float scale2)
{
  const int wave = threadIdx.x >> 6, lane = threadIdx.x & 63;
  const int j = blockIdx.x * 4 + wave;
  const int s0 = rptr[j], s1 = rptr[j + 1];
  const size_t coff = (size_t)lane * 8;
  float acc[8] = {0.f, 0.f, 0.f, 0.f, 0.f, 0.f, 0.f, 0.f};
  for (int s = s0; s < s1; ++s) {
    int src = rsrc[s];
    uint4 v = *(const uint4*)&tin[(size_t)src * 512 + coff];
    acc[0] += bf_lo(v.x); acc[1] += bf_hi(v.x);
    acc[2] += bf_lo(v.y); acc[3] += bf_hi(v.y);
    acc[4] += bf_lo(v.z); acc[5] += bf_hi(v.z);
    acc[6] += bf_lo(v.w); acc[7] += bf_hi(v.w);
  }
  float pv[8] = {0.f, 0.f, 0.f, 0.f, 0.f, 0.f, 0.f, 0.f};
  if (tprev != nullptr) {
    uint4 p = *(const uint4*)&tprev[(size_t)j * 512 + coff];
    pv[0] = bf_lo(p.x); pv[1] = bf_hi(p.x);
    pv[2] = bf_lo(p.y); pv[3] = bf_hi(p.y);
    pv[4] = bf_lo(p.z); pv[5] = bf_hi(p.z);
    pv[6] = bf_lo(p.w); pv[7] = bf_hi(p.w);
  }
  unsigned short o16[8];
#pragma unroll
  for (int q = 0; q < 8; ++q) o16[q] = f2bf(scale2 * acc[q] - pv[q]);
  uint4 o;
  o.x = (unsigned int)o16[0] | ((unsigned int)o16[1] << 16);
  o.y = (unsigned int)o16[2] | ((unsigned int)o16[3] << 16);
  o.z = (unsigned int)o16[4] | ((unsigned int)o16[5] << 16);
  o.w = (unsigned int)o16[6] | ((unsigned int)o16[7] << 16);
  *(uint4*)&tout[(size_t)j * 512 + coff] = o;
}

// ---------------- GEMM: C[o][n] = sum_kc A[n][kc] * B[kc][o] + bias[o] ----------------
// A = TxAll bf16: 5 blocks of [10000][512] (+pad). B^T = thetabT bf16 [512][2560].
__global__ __launch_bounds__(256) void gemm_kernel(
    const unsigned short* __restrict__ A,
    const unsigned short* __restrict__ Bt,
    const float* __restrict__ bias,
    float* __restrict__ C)
{
  __shared__ __align__(16) char smem[64 * 132 * 4];   // 33792B: tiles(32KB) / epilogue(33KB)
  unsigned short* As = (unsigned short*)smem;         // [128][64] bf16
  unsigned short* Bs = As + 128 * 64;                 // [128 o][64 k] bf16
  float* eps = (float*)smem;                          // [64 o][132] f32

  const int tid = threadIdx.x;
  const int wave = tid >> 6, lane = tid & 63;
  const int l15 = lane & 15, hi = lane >> 4;
  const int wr = wave >> 1, wc = wave & 1;
  const int n0 = blockIdx.x * 128;
  const int o0 = blockIdx.y * 128;

  f32x4 acc[4][4];
#pragma unroll
  for (int a = 0; a < 4; ++a)
#pragma unroll
    for (int b = 0; b < 4; ++b) acc[a][b] = (f32x4){0.f, 0.f, 0.f, 0.f};

  for (int kt = 0; kt < 40; ++kt) {
    const int k0 = kt * 64;
    const int ko = k0 >> 9;
    const int c0 = k0 & 511;
    const unsigned short* Ab = A + (size_t)ko * ((size_t)N_NODES * 512);
#pragma unroll
    for (int q = 0; q < 4; ++q) {
      int idx = (wave * 4 + q) * 64 + lane;     // 16B unit id, 0..1023
      int r = idx >> 3, u = idx & 7;
      gll16(Ab + (size_t)(n0 + r) * 512 + c0 + u * 8, As + (size_t)(wave * 4 + q) * 512);
    }
#pragma unroll
    for (int q = 0; q < 4; ++q) {
      int idx = (wave * 4 + q) * 64 + lane;
      int r = idx >> 3, u = idx & 7;
      gll16(Bt + (size_t)(o0 + r) * 2560 + k0 + u * 8, Bs + (size_t)(wave * 4 + q) * 512);
    }
    __syncthreads();
#pragma unroll
    for (int kk = 0; kk < 2; ++kk) {
      bf16x8 af[4], bfr[4];
#pragma unroll
      for (int mi = 0; mi < 4; ++mi)
        af[mi] = *(const bf16x8*)(As + ((wr * 64 + mi * 16 + l15) * 64 + kk * 32 + hi * 8));
#pragma unroll
      for (int ni = 0; ni < 4; ++ni)
        bfr[ni] = *(const bf16x8*)(Bs + ((wc * 64 + ni * 16 + l15) * 64 + kk * 32 + hi * 8));
#pragma unroll
      for (int mi = 0; mi < 4; ++mi)
#pragma unroll
        for (int ni = 0; ni < 4; ++ni)
          acc[mi][ni] = __builtin_amdgcn_mfma_f32_16x16x32_bf16(af[mi], bfr[ni], acc[mi][ni], 0, 0, 0);
    }
    __syncthreads();
  }

  // epilogue: LDS-transposed coalesced store of C[o][n] + bias
#pragma unroll
  for (int h = 0; h < 2; ++h) {
    __syncthreads();
    if (wc == h) {
#pragma unroll
      for (int mi = 0; mi < 4; ++mi)
#pragma unroll
        for (int ni = 0; ni < 4; ++ni) {
          int o_l = ni * 16 + l15;                   // 0..63 within half
          int nb = wr * 64 + mi * 16 + hi * 4;       // 0..124, x4 aligned
          *(f32x4*)&eps[o_l * 132 + nb] = acc[mi][ni];
        }
    }
    __syncthreads();
#pragma unroll
    for (int q = 0; q < 8; ++q) {
      int unit = q * 256 + tid;                      // 2048 float4 units
      int o_l = unit >> 5, nu = unit & 31;
      int n = n0 + nu * 4;
      if (n < N_NODES) {
        int o = o0 + h * 64 + o_l;
        f32x4 v = *(const f32x4*)&eps[o_l * 132 + nu * 4];
        float bo = bias[o];
        v = v + bo;
        *(f32x4*)&C[(size_t)o * N_NODES + n] = v;
      }
    }
  }
}

extern "C" void kernel_launch(void* const* d_in, const int* in_sizes, int n_in,
                              void* d_out, int out_size, void* d_ws, size_t ws_size,
                              hipStream_t stream)
{
  const float* x        = (const float*)d_in[0];   // [512][10000]
  const float* position = (const float*)d_in[1];   // [10000][3]
  const float* theta    = (const float*)d_in[2];   // [5][512][512]
  const float* bias     = (const float*)d_in[3];   // [512]

  char* ws = (char*)d_ws;
  size_t off = 0;
  auto alloc = [&](size_t bytes) -> void* {
    void* p = ws + off;
    off = (off + bytes + 255) & ~(size_t)255;
    return p;
  };
  unsigned short* TxAll   = (unsigned short*)alloc(5ull * N_NODES * 512 * 2 + 131072); // +128-row pad
  unsigned short* thetabT = (unsigned short*)alloc(512ull * 2560 * 2);
  float4* pos4 = (float4*)alloc((size_t)POS4_PAD * 16);
  int* knn    = (int*)alloc((size_t)NEDGE * 4);
  int* rptr   = (int*)alloc((size_t)(N_NODES + 1) * 4);
  int* counts = (int*)alloc((size_t)N_NODES * 4);
  int* cursor = (int*)alloc((size_t)N_NODES * 4);
  int* rsrc   = (int*)alloc((size_t)NEDGE * 4);
  if (ws_size < off) return;   // insufficient scratch

  // theta [5][512][512] -> thetabT [o=512][kc=2560]
  transpose_f32_bf16<<<dim3(8, 8, 5), 256, 0, stream>>>(
      theta, thetabT, 512, 512, 2560, (size_t)512 * 512, 512);
  // x [512][10000] -> Tx0 [10000][512]
  transpose_f32_bf16<<<dim3(157, 8, 1), 256, 0, stream>>>(
      x, TxAll, 512, N_NODES, 512, 0, 0);

  pos4_kernel<<<40, 256, 0, stream>>>(position, pos4);
  knn_kernel<<<2500, 256, 0, stream>>>(pos4, knn);

  hipMemsetAsync(counts, 0, (size_t)N_NODES * 4, stream);
  hipMemsetAsync(cursor, 0, (size_t)N_NODES * 4, stream);
  count_kernel<<<(NEDGE + 255) / 256, 256, 0, stream>>>(knn, counts);
  scan_kernel<<<1, 256, 0, stream>>>(counts, rptr);
  fill_kernel<<<(NEDGE + 255) / 256, 256, 0, stream>>>(knn, rptr, cursor, rsrc);
  sort_kernel<<<(N_NODES + 255) / 256, 256, 0, stream>>>(rptr, rsrc);

  unsigned short* Tx0 = TxAll;
  unsigned short* Tx1 = TxAll + 1ull * N_NODES * 512;
  unsigned short* Tx2 = TxAll + 2ull * N_NODES * 512;
  unsigned short* Tx3 = TxAll + 3ull * N_NODES * 512;
  unsigned short* Tx4 = TxAll + 4ull * N_NODES * 512;

  // Tx1 = prop(Tx0) = -0.05*sum ; Tx_k = 2*prop(Tx_{k-1}) - Tx_{k-2} = -0.10*sum - prev
  prop_kernel<<<2500, 256, 0, stream>>>(Tx0, nullptr, Tx1, rptr, rsrc, -0.05f);
  prop_kernel<<<2500, 256, 0, stream>>>(Tx1, Tx0,     Tx2, rptr, rsrc, -0.10f);
  prop_kernel<<<2500, 256, 0, stream>>>(Tx2, Tx1,     Tx3, rptr, rsrc, -0.10f);
  prop_kernel<<<2500, 256, 0, stream>>>(Tx3, Tx2,     Tx4, rptr, rsrc, -0.10f);

  gemm_kernel<<<dim3(79, 4), 256, 0, stream>>>(TxAll, thetabT, bias, (float*)d_out);
}

// Round 6
// 429.089 us; speedup vs baseline: 1.3530x; 1.1374x over previous
//
// Round 6: kNN two-phase — phase 1: per-lane top-8 on raw f32 distances via
// v_med3_f32 insert network (8 VALU/candidate); merge: exact 20th value (tau);
// phase 2: ballot-compacted index recovery {d<tau} then {d==tau}. Rest
// unchanged from the round-5 pass (488us total, knn was 200us @ 156 instr/cand).
#include <hip/hip_runtime.h>
#include <hip/hip_bf16.h>
#include <cstdint>
#include <cstddef>

#define N_NODES 10000
#define KNN_K 20
#define NEDGE (N_NODES * KNN_K)
#define NBATCH 157                 // ceil(10000/64)
#define POS4_PAD 10048             // 157*64

using bf16x8 = __attribute__((ext_vector_type(8))) short;
using f32x4  = __attribute__((ext_vector_type(4))) float;

__device__ __forceinline__ float bf_lo(unsigned int u) {
  union { unsigned int i; float f; } c; c.i = u << 16; return c.f;
}
__device__ __forceinline__ float bf_hi(unsigned int u) {
  union { unsigned int i; float f; } c; c.i = u & 0xFFFF0000u; return c.f;
}
__device__ __forceinline__ unsigned short f2bf(float f) {
  union { float f; unsigned int i; } c; c.f = f;
  unsigned int u = c.i;
  u += 0x7FFFu + ((u >> 16) & 1u);   // RNE
  return (unsigned short)(u >> 16);
}

__device__ __forceinline__ void gll16(const void* g, void* l) {
  __builtin_amdgcn_global_load_lds(
      (const __attribute__((address_space(1))) unsigned int*)g,
      (__attribute__((address_space(3))) unsigned int*)l,
      16, 0, 0);
}

// ---------------- transpose f32 [srows][scols] -> bf16 dst[col][dcol0 + row] ----------------
__global__ __launch_bounds__(256) void transpose_f32_bf16(
    const float* __restrict__ src0, unsigned short* __restrict__ dst,
    int srows, int scols, int dstride, size_t slice_elems, int dcol_per_slice)
{
  __shared__ float lds[64 * 65];
  const int z = blockIdx.z;
  const float* src = src0 + (size_t)z * slice_elems;
  const int dcol0 = z * dcol_per_slice;
  const int c0 = blockIdx.x * 64;
  const int r0 = blockIdx.y * 64;
  const int tid = threadIdx.x;
#pragma unroll
  for (int q = 0; q < 4; ++q) {
    int unit = q * 256 + tid;            // 1024 float4 units
    int rr = unit >> 4;                  // 0..63
    int cu = unit & 15;                  // 0..15
    int r = r0 + rr, c = c0 + cu * 4;
    float4 v = make_float4(0.f, 0.f, 0.f, 0.f);
    if (r < srows && c + 3 < scols) v = *(const float4*)&src[(size_t)r * scols + c];
    lds[rr * 65 + cu * 4 + 0] = v.x;
    lds[rr * 65 + cu * 4 + 1] = v.y;
    lds[rr * 65 + cu * 4 + 2] = v.z;
    lds[rr * 65 + cu * 4 + 3] = v.w;
  }
  __syncthreads();
#pragma unroll
  for (int q = 0; q < 2; ++q) {
    int unit = q * 256 + tid;            // 512 units of 8 bf16
    int cl = unit >> 3;                  // src col within tile (= dst row)
    int ru = unit & 7;
    int c = c0 + cl;
    if (c < scols) {
      unsigned short tmp[8];
#pragma unroll
      for (int j = 0; j < 8; ++j) tmp[j] = f2bf(lds[(ru * 8 + j) * 65 + cl]);
      uint4 o;
      o.x = (unsigned int)tmp[0] | ((unsigned int)tmp[1] << 16);
      o.y = (unsigned int)tmp[2] | ((unsigned int)tmp[3] << 16);
      o.z = (unsigned int)tmp[4] | ((unsigned int)tmp[5] << 16);
      o.w = (unsigned int)tmp[6] | ((unsigned int)tmp[7] << 16);
      *(uint4*)&dst[(size_t)c * dstride + dcol0 + r0 + ru * 8] = o;
    }
  }
}

// ---------------- pos4: pack (x,y,z,|p|^2); pad rows get w=+INF ----------------
__global__ __launch_bounds__(256) void pos4_kernel(
    const float* __restrict__ pos, float4* __restrict__ pos4)
{
  int c = blockIdx.x * 256 + threadIdx.x;
  if (c < POS4_PAD) {
    float4 v;
    if (c < N_NODES) {
      float x = pos[c * 3 + 0], y = pos[c * 3 + 1], z = pos[c * 3 + 2];
      v = make_float4(x, y, z, x * x + y * y + z * z);
    } else {
      v = make_float4(0.f, 0.f, 0.f, __builtin_inff());   // d -> +INF
    }
    pos4[c] = v;
  }
}

// identical expression in both phases -> bit-identical distances
__device__ __forceinline__ float knn_dist(float4 pi, float4 s) {
  float dot = fmaf(pi.x, s.x, fmaf(pi.y, s.y, pi.z * s.z));
  return fmaf(-2.0f, dot, pi.w + s.w);
}

// ---------------- kNN: wave/node; f32 top-8 via med3; tau; index recovery ----------------
__global__ __launch_bounds__(256) void knn_kernel(
    const float4* __restrict__ pos4, int* __restrict__ knn_out)
{
  const int lane = threadIdx.x & 63, wave = threadIdx.x >> 6;
  const int i = blockIdx.x * 4 + wave;
  const float4 pi = pos4[i];
  const float INF = __builtin_inff();

  float r0 = INF, r1 = INF, r2 = INF, r3 = INF;
  float r4 = INF, r5 = INF, r6 = INF, r7 = INF;

  // phase 1: per-lane top-8 of distances (branchless med3 insert network)
#pragma unroll 4
  for (int b = 0; b < NBATCH; ++b) {
    const int cid = b * 64 + lane;
    const float4 s = pos4[cid];
    float d = knn_dist(pi, s);                    // pad rows: +INF
    float k = (cid == i) ? INF : d;               // exclude self
    // r_j = median(k, r_{j-1}, r_j) == min(r_j, max(r_{j-1}, k))  [r asc]
    asm("v_med3_f32 %0, %1, %2, %3" : "=v"(r7) : "v"(k), "v"(r6), "v"(r7));
    asm("v_med3_f32 %0, %1, %2, %3" : "=v"(r6) : "v"(k), "v"(r5), "v"(r6));
    asm("v_med3_f32 %0, %1, %2, %3" : "=v"(r5) : "v"(k), "v"(r4), "v"(r5));
    asm("v_med3_f32 %0, %1, %2, %3" : "=v"(r4) : "v"(k), "v"(r3), "v"(r4));
    asm("v_med3_f32 %0, %1, %2, %3" : "=v"(r3) : "v"(k), "v"(r2), "v"(r3));
    asm("v_med3_f32 %0, %1, %2, %3" : "=v"(r2) : "v"(k), "v"(r1), "v"(r2));
    asm("v_med3_f32 %0, %1, %2, %3" : "=v"(r1) : "v"(k), "v"(r0), "v"(r1));
    r0 = fminf(r0, k);
  }

  // merge: 20 duplicate-safe extract-min rounds -> tau = exact 20th smallest
  float tau = INF;
#pragma unroll
  for (int r = 0; r < KNN_K; ++r) {
    float m = r0;
    m = fminf(m, __shfl_xor(m, 1));
    m = fminf(m, __shfl_xor(m, 2));
    m = fminf(m, __shfl_xor(m, 4));
    m = fminf(m, __shfl_xor(m, 8));
    m = fminf(m, __shfl_xor(m, 16));
    m = fminf(m, __shfl_xor(m, 32));
    unsigned long long who = __ballot(r0 == m);
    int srcl = __ffsll(who) - 1;                  // pop exactly one holder
    if (lane == srcl) {
      r0 = r1; r1 = r2; r2 = r3; r3 = r4; r4 = r5; r5 = r6; r6 = r7; r7 = INF;
    }
    tau = m;                                       // after loop: 20th smallest
  }

  // phase 2: recover indices — all {d < tau}, then {d == tau} lowest-index first
  int cnt = 0;
  for (int b = 0; b < NBATCH; ++b) {
    const int cid = b * 64 + lane;
    const float4 s = pos4[cid];
    float d = knn_dist(pi, s);
    bool valid = (cid != i);                      // pad rows: d=INF, self-excluded
    unsigned long long less = __ballot(valid && d < tau);
    unsigned long long eq   = __ballot(valid && d == tau);
    if (less) {
      if (valid && d < tau) {
        int pos = cnt + (int)__popcll(less & ((1ull << lane) - 1ull));
        if (pos < KNN_K) knn_out[i * KNN_K + pos] = cid;
      }
      cnt += (int)__popcll(less);
    }
    if (eq && cnt < KNN_K) {
      if (valid && d == tau) {
        int pos = cnt + (int)__popcll(eq & ((1ull << lane) - 1ull));
        if (pos < KNN_K) knn_out[i * KNN_K + pos] = cid;
      }
      cnt = min(KNN_K, cnt + (int)__popcll(eq));
    }
  }
}

// ---------------- reverse-CSR build ----------------
__global__ __launch_bounds__(256) void count_kernel(
    const int* __restrict__ knn, int* __restrict__ counts)
{
  int e = blockIdx.x * 256 + threadIdx.x;
  if (e < NEDGE) atomicAdd(&counts[knn[e]], 1);
}

__global__ __launch_bounds__(256) void scan_kernel(
    const int* __restrict__ counts, int* __restrict__ rptr)
{
  __shared__ int part[256];
  const int tid = threadIdx.x;
  const int base = tid * 40;                       // 256*40 = 10240 >= 10000
  int s = 0;
  for (int q = 0; q < 40; ++q) { int idx = base + q; if (idx < N_NODES) s += counts[idx]; }
  part[tid] = s;
  __syncthreads();
  for (int off = 1; off < 256; off <<= 1) {
    int add = (tid >= off) ? part[tid - off] : 0;
    __syncthreads();
    part[tid] += add;
    __syncthreads();
  }
  int run = part[tid] - s;                         // exclusive offset
  for (int q = 0; q < 40; ++q) {
    int idx = base + q;
    if (idx < N_NODES) { rptr[idx] = run; run += counts[idx]; }
  }
  if (tid == 255) rptr[N_NODES] = run;
}

__global__ __launch_bounds__(256) void fill_kernel(
    const int* __restrict__ knn, const int* __restrict__ rptr,
    int* __restrict__ cursor, int* __restrict__ rsrc)
{
  int e = blockIdx.x * 256 + threadIdx.x;
  if (e < NEDGE) {
    int j = knn[e];
    int i = e / KNN_K;
    int p = atomicAdd(&cursor[j], 1);
    rsrc[rptr[j] + p] = i;
  }
}

// sort each reverse-adjacency list -> deterministic gather order
__global__ __launch_bounds__(256) void sort_kernel(
    const int* __restrict__ rptr, int* __restrict__ rsrc)
{
  int j = blockIdx.x * 256 + threadIdx.x;
  if (j < N_NODES) {
    int s0 = rptr[j], s1 = rptr[j + 1];
    for (int a = s0 + 1; a < s1; ++a) {
      int v = rsrc[a];
      int b = a - 1;
      while (b >= s0 && rsrc[b] > v) { rsrc[b + 1] = rsrc[b]; --b; }
      rsrc[b + 1] = v;
    }
  }
}

// ---------------- prop: out[j] = scale2 * sum_{i in rev(j)} t[i]  - prev[j] ----------------
__global__ __launch_bounds__(256) void prop_kernel(
    const unsigned short* __restrict__ tin, const unsigned short* __restrict__ tprev,
    unsigned short* __restrict__ tout, const int* __restrict__ rptr,
    const int* __restrict__ rsrc, float scale2)
{
  const int wave = threadIdx.x >> 6, lane = threadIdx.x & 63;
  const int j = blockIdx.x * 4 + wave;
  const int s0 = rptr[j], s1 = rptr[j + 1];
  const size_t coff = (size_t)lane * 8;
  float acc[8] = {0.f, 0.f, 0.f, 0.f, 0.f, 0.f, 0.f, 0.f};
  for (int s = s0; s < s1; ++s) {
    int src = rsrc[s];
    uint4 v = *(const uint4*)&tin[(size_t)src * 512 + coff];
    acc[0] += bf_lo(v.x); acc[1] += bf_hi(v.x);
    acc[2] += bf_lo(v.y); acc[3] += bf_hi(v.y);
    acc[4] += bf_lo(v.z); acc[5] += bf_hi(v.z);
    acc[6] += bf_lo(v.w); acc[7] += bf_hi(v.w);
  }
  float pv[8] = {0.f, 0.f, 0.f, 0.f, 0.f, 0.f, 0.f, 0.f};
  if (tprev != nullptr) {
    uint4 p = *(const uint4*)&tprev[(size_t)j * 512 + coff];
    pv[0] = bf_lo(p.x); pv[1] = bf_hi(p.x);
    pv[2] = bf_lo(p.y); pv[3] = bf_hi(p.y);
    pv[4] = bf_lo(p.z); pv[5] = bf_hi(p.z);
    pv[6] = bf_lo(p.w); pv[7] = bf_hi(p.w);
  }
  unsigned short o16[8];
#pragma unroll
  for (int q = 0; q < 8; ++q) o16[q] = f2bf(scale2 * acc[q] - pv[q]);
  uint4 o;
  o.x = (unsigned int)o16[0] | ((unsigned int)o16[1] << 16);
  o.y = (unsigned int)o16[2] | ((unsigned int)o16[3] << 16);
  o.z = (unsigned int)o16[4] | ((unsigned int)o16[5] << 16);
  o.w = (unsigned int)o16[6] | ((unsigned int)o16[7] << 16);
  *(uint4*)&tout[(size_t)j * 512 + coff] = o;
}

// ---------------- GEMM: C[o][n] = sum_kc A[n][kc] * B[kc][o] + bias[o] ----------------
// A = TxAll bf16: 5 blocks of [10000][512] (+pad). B^T = thetabT bf16 [512][2560].
__global__ __launch_bounds__(256) void gemm_kernel(
    const unsigned short* __restrict__ A,
    const unsigned short* __restrict__ Bt,
    const float* __restrict__ bias,
    float* __restrict__ C)
{
  __shared__ __align__(16) char smem[64 * 132 * 4];   // 33792B: tiles(32KB) / epilogue(33KB)
  unsigned short* As = (unsigned short*)smem;         // [128][64] bf16
  unsigned short* Bs = As + 128 * 64;                 // [128 o][64 k] bf16
  float* eps = (float*)smem;                          // [64 o][132] f32

  const int tid = threadIdx.x;
  const int wave = tid >> 6, lane = tid & 63;
  const int l15 = lane & 15, hi = lane >> 4;
  const int wr = wave >> 1, wc = wave & 1;
  const int n0 = blockIdx.x * 128;
  const int o0 = blockIdx.y * 128;

  f32x4 acc[4][4];
#pragma unroll
  for (int a = 0; a < 4; ++a)
#pragma unroll
    for (int b = 0; b < 4; ++b) acc[a][b] = (f32x4){0.f, 0.f, 0.f, 0.f};

  for (int kt = 0; kt < 40; ++kt) {
    const int k0 = kt * 64;
    const int ko = k0 >> 9;
    const int c0 = k0 & 511;
    const unsigned short* Ab = A + (size_t)ko * ((size_t)N_NODES * 512);
#pragma unroll
    for (int q = 0; q < 4; ++q) {
      int idx = (wave * 4 + q) * 64 + lane;     // 16B unit id, 0..1023
      int r = idx >> 3, u = idx & 7;
      gll16(Ab + (size_t)(n0 + r) * 512 + c0 + u * 8, As + (size_t)(wave * 4 + q) * 512);
    }
#pragma unroll
    for (int q = 0; q < 4; ++q) {
      int idx = (wave * 4 + q) * 64 + lane;
      int r = idx >> 3, u = idx & 7;
      gll16(Bt + (size_t)(o0 + r) * 2560 + k0 + u * 8, Bs + (size_t)(wave * 4 + q) * 512);
    }
    __syncthreads();
#pragma unroll
    for (int kk = 0; kk < 2; ++kk) {
      bf16x8 af[4], bfr[4];
#pragma unroll
      for (int mi = 0; mi < 4; ++mi)
        af[mi] = *(const bf16x8*)(As + ((wr * 64 + mi * 16 + l15) * 64 + kk * 32 + hi * 8));
#pragma unroll
      for (int ni = 0; ni < 4; ++ni)
        bfr[ni] = *(const bf16x8*)(Bs + ((wc * 64 + ni * 16 + l15) * 64 + kk * 32 + hi * 8));
#pragma unroll
      for (int mi = 0; mi < 4; ++mi)
#pragma unroll
        for (int ni = 0; ni < 4; ++ni)
          acc[mi][ni] = __builtin_amdgcn_mfma_f32_16x16x32_bf16(af[mi], bfr[ni], acc[mi][ni], 0, 0, 0);
    }
    __syncthreads();
  }

  // epilogue: LDS-transposed coalesced store of C[o][n] + bias
#pragma unroll
  for (int h = 0; h < 2; ++h) {
    __syncthreads();
    if (wc == h) {
#pragma unroll
      for (int mi = 0; mi < 4; ++mi)
#pragma unroll
        for (int ni = 0; ni < 4; ++ni) {
          int o_l = ni * 16 + l15;                   // 0..63 within half
          int nb = wr * 64 + mi * 16 + hi * 4;       // 0..124, x4 aligned
          *(f32x4*)&eps[o_l * 132 + nb] = acc[mi][ni];
        }
    }
    __syncthreads();
#pragma unroll
    for (int q = 0; q < 8; ++q) {
      int unit = q * 256 + tid;                      // 2048 float4 units
      int o_l = unit >> 5, nu = unit & 31;
      int n = n0 + nu * 4;
      if (n < N_NODES) {
        int o = o0 + h * 64 + o_l;
        f32x4 v = *(const f32x4*)&eps[o_l * 132 + nu * 4];
        float bo = bias[o];
        v = v + bo;
        *(f32x4*)&C[(size_t)o * N_NODES + n] = v;
      }
    }
  }
}

extern "C" void kernel_launch(void* const* d_in, const int* in_sizes, int n_in,
                              void* d_out, int out_size, void* d_ws, size_t ws_size,
                              hipStream_t stream)
{
  const float* x        = (const float*)d_in[0];   // [512][10000]
  const float* position = (const float*)d_in[1];   // [10000][3]
  const float* theta    = (const float*)d_in[2];   // [5][512][512]
  const float* bias     = (const float*)d_in[3];   // [512]

  char* ws = (char*)d_ws;
  size_t off = 0;
  auto alloc = [&](size_t bytes) -> void* {
    void* p = ws + off;
    off = (off + bytes + 255) & ~(size_t)255;
    return p;
  };
  unsigned short* TxAll   = (unsigned short*)alloc(5ull * N_NODES * 512 * 2 + 131072); // +128-row pad
  unsigned short* thetabT = (unsigned short*)alloc(512ull * 2560 * 2);
  float4* pos4 = (float4*)alloc((size_t)POS4_PAD * 16);
  int* knn    = (int*)alloc((size_t)NEDGE * 4);
  int* rptr   = (int*)alloc((size_t)(N_NODES + 1) * 4);
  int* counts = (int*)alloc((size_t)N_NODES * 4);
  int* cursor = (int*)alloc((size_t)N_NODES * 4);
  int* rsrc   = (int*)alloc((size_t)NEDGE * 4);
  if (ws_size < off) return;   // insufficient scratch

  // theta [5][512][512] -> thetabT [o=512][kc=2560]
  transpose_f32_bf16<<<dim3(8, 8, 5), 256, 0, stream>>>(
      theta, thetabT, 512, 512, 2560, (size_t)512 * 512, 512);
  // x [512][10000] -> Tx0 [10000][512]
  transpose_f32_bf16<<<dim3(157, 8, 1), 256, 0, stream>>>(
      x, TxAll, 512, N_NODES, 512, 0, 0);

  pos4_kernel<<<40, 256, 0, stream>>>(position, pos4);
  knn_kernel<<<2500, 256, 0, stream>>>(pos4, knn);

  hipMemsetAsync(counts, 0, (size_t)N_NODES * 4, stream);
  hipMemsetAsync(cursor, 0, (size_t)N_NODES * 4, stream);
  count_kernel<<<(NEDGE + 255) / 256, 256, 0, stream>>>(knn, counts);
  scan_kernel<<<1, 256, 0, stream>>>(counts, rptr);
  fill_kernel<<<(NEDGE + 255) / 256, 256, 0, stream>>>(knn, rptr, cursor, rsrc);
  sort_kernel<<<(N_NODES + 255) / 256, 256, 0, stream>>>(rptr, rsrc);

  unsigned short* Tx0 = TxAll;
  unsigned short* Tx1 = TxAll + 1ull * N_NODES * 512;
  unsigned short* Tx2 = TxAll + 2ull * N_NODES * 512;
  unsigned short* Tx3 = TxAll + 3ull * N_NODES * 512;
  unsigned short* Tx4 = TxAll + 4ull * N_NODES * 512;

  // Tx1 = prop(Tx0) = -0.05*sum ; Tx_k = 2*prop(Tx_{k-1}) - Tx_{k-2} = -0.10*sum - prev
  prop_kernel<<<2500, 256, 0, stream>>>(Tx0, nullptr, Tx1, rptr, rsrc, -0.05f);
  prop_kernel<<<2500, 256, 0, stream>>>(Tx1, Tx0,     Tx2, rptr, rsrc, -0.10f);
  prop_kernel<<<2500, 256, 0, stream>>>(Tx2, Tx1,     Tx3, rptr, rsrc, -0.10f);
  prop_kernel<<<2500, 256, 0, stream>>>(Tx3, Tx2,     Tx4, rptr, rsrc, -0.10f);

  gemm_kernel<<<dim3(79, 4), 256, 0, stream>>>(TxAll, thetabT, bias, (float*)d_out);
}